// Round 12
// baseline (1175.977 us; speedup 1.0000x reference)
//
#include <hip/hip_runtime.h>
#include <hip/hip_bf16.h>
#include <stdint.h>

// CirculantLinear == dense GEMM: y[b,o] = sum_n x[b,n]*rows[o,n] + bias[o],
// rows[o,n] = c[o, (4096-n) & 4095]. M=8192, N=4096, K=4096. fp32 in/out.
// R9: i8 256^2/BK128, 140us GEMM = exact serial sum MFMA(171k cy)+LDS(163k).
// R10: reg-squeeze spill disaster. R11: 128^2 tile -> LDS traffic 2x, worse.
// R12: R9 base + anti-phase wave groups on a 4-slot ring (32KB/kstep=64):
//      even waves {read(s); MFMA(s)}, odd waves {MFMA(s) from regs;
//      read(s+1)} between the SAME barriers -> the two waves on each SIMD
//      drive LDS and MFMA pipes concurrently (m114). Stage leads by 3 slots,
//      vmcnt(4)/body certifies slot s+2; odd parity (w>>2)&1 pairs one
//      even+one odd wave per SIMD under the w%4 SIMD map.

#define B_DIM  8192
#define OUT_DIM 4096
#define IN_DIM  4096

typedef __attribute__((ext_vector_type(4))) int i32x4;

// ---- fused quantization kernel ------------------------------------------

__global__ void quant_fused_kernel(const float* __restrict__ x,
                                   const float* __restrict__ c,
                                   int8_t* __restrict__ xq,
                                   int8_t* __restrict__ cq,
                                   float* __restrict__ sx,
                                   float* __restrict__ sc) {
  const int row = blockIdx.x;
  const int t = threadIdx.x;
  __shared__ float sm[4];
  float vals[16];

  if (row < B_DIM) {
    const float4* src = (const float4*)(x + (size_t)row * IN_DIM + t * 16);
#pragma unroll
    for (int j = 0; j < 4; ++j) {
      float4 v = src[j];
      vals[4 * j + 0] = v.x; vals[4 * j + 1] = v.y;
      vals[4 * j + 2] = v.z; vals[4 * j + 3] = v.w;
    }
  } else {
    const float* crow = c + (size_t)(row - B_DIM) * IN_DIM;
    const int n0 = t * 16;
    if (t == 0) {
#pragma unroll
      for (int j = 0; j < 16; ++j) vals[j] = crow[(IN_DIM - j) & (IN_DIM - 1)];
    } else {
      const float4* src = (const float4*)(crow + (IN_DIM - n0 - 15));
      float f[16];
#pragma unroll
      for (int j = 0; j < 4; ++j) {
        float4 v = src[j];
        f[4 * j + 0] = v.x; f[4 * j + 1] = v.y;
        f[4 * j + 2] = v.z; f[4 * j + 3] = v.w;
      }
#pragma unroll
      for (int j = 0; j < 16; ++j) vals[j] = f[15 - j];
    }
  }

  float m = 0.f;
#pragma unroll
  for (int j = 0; j < 16; ++j) m = fmaxf(m, fabsf(vals[j]));
#pragma unroll
  for (int k = 32; k; k >>= 1) m = fmaxf(m, __shfl_xor(m, k));
  if ((t & 63) == 0) sm[t >> 6] = m;
  __syncthreads();
  m = fmaxf(fmaxf(sm[0], sm[1]), fmaxf(sm[2], sm[3]));

  const float inv = m > 0.f ? 127.0f / m : 0.f;
  const float scale = m * (1.0f / 127.0f);

  int4 packed;
  int* pw = (int*)&packed;
#pragma unroll
  for (int g = 0; g < 4; ++g) {
    int wbits = 0;
#pragma unroll
    for (int j = 0; j < 4; ++j) {
      float q = rintf(vals[g * 4 + j] * inv);
      q = fminf(fmaxf(q, -127.f), 127.f);
      wbits |= (((int)q) & 0xff) << (8 * j);
    }
    pw[g] = wbits;
  }

  if (row < B_DIM) {
    *(int4*)(xq + (size_t)row * IN_DIM + t * 16) = packed;
    if (t == 0) sx[row] = scale;
  } else {
    *(int4*)(cq + (size_t)(row - B_DIM) * IN_DIM + t * 16) = packed;
    if (t == 0) sc[row - B_DIM] = scale;
  }
}

// ---- GEMM ---------------------------------------------------------------

__device__ __forceinline__ void async_copy16(const void* g, void* l) {
  __builtin_amdgcn_global_load_lds(
      (const __attribute__((address_space(1))) void*)g,
      (__attribute__((address_space(3))) void*)l, 16, 0, 0);
}

// LDS: 4 ring slots x 32KB. Slot s = kstep s (64 i8 K-cols):
// [A 256x64B | B 256x64B], chunk-XOR swizzle phys_chunk = logical ^
// ((row>>1)&3) (measured 0 conflicts); stage side applies the inverse via
// the per-lane GLOBAL address (LDS dest linear for global_load_lds).

#define STAGE(SLOT, koff)                                                    \
  async_copy16(sA + (koff), smem + (SLOT)*32768 + w * 1024);                 \
  async_copy16(sA + (koff) + 128 * (size_t)IN_DIM,                           \
               smem + (SLOT)*32768 + 8192 + w * 1024);                       \
  async_copy16(sB + (koff), smem + (SLOT)*32768 + 16384 + w * 1024);         \
  async_copy16(sB + (koff) + 128 * (size_t)IN_DIM,                           \
               smem + (SLOT)*32768 + 16384 + 8192 + w * 1024)

#define RD_A(SLOT, i)                                                        \
  (*(const i32x4*)(smem + (SLOT)*32768 + aRd + (i) * 1024))
#define RD_B(SLOT, i)                                                        \
  (*(const i32x4*)(smem + (SLOT)*32768 + 16384 + bRd + (i) * 1024))

#define READF(SLOT)                                                          \
  bF0 = RD_B(SLOT, 0); bF1 = RD_B(SLOT, 1);                                  \
  bF2 = RD_B(SLOT, 2); bF3 = RD_B(SLOT, 3);                                  \
  aF0 = RD_A(SLOT, 0); aF1 = RD_A(SLOT, 1);                                  \
  aF2 = RD_A(SLOT, 2); aF3 = RD_A(SLOT, 3);                                  \
  aF4 = RD_A(SLOT, 4); aF5 = RD_A(SLOT, 5);                                  \
  aF6 = RD_A(SLOT, 6); aF7 = RD_A(SLOT, 7)

#define MM(a, b, r, cc)                                                      \
  acc[r][cc] = __builtin_amdgcn_mfma_i32_16x16x64_i8(a, b, acc[r][cc], 0, 0, 0)

#define MFMA32                                                               \
  __builtin_amdgcn_s_setprio(1);                                             \
  MM(aF0, bF0, 0, 0); MM(aF0, bF1, 0, 1); MM(aF0, bF2, 0, 2); MM(aF0, bF3, 0, 3); \
  MM(aF1, bF0, 1, 0); MM(aF1, bF1, 1, 1); MM(aF1, bF2, 1, 2); MM(aF1, bF3, 1, 3); \
  MM(aF2, bF0, 2, 0); MM(aF2, bF1, 2, 1); MM(aF2, bF2, 2, 2); MM(aF2, bF3, 2, 3); \
  MM(aF3, bF0, 3, 0); MM(aF3, bF1, 3, 1); MM(aF3, bF2, 3, 2); MM(aF3, bF3, 3, 3); \
  MM(aF4, bF0, 4, 0); MM(aF4, bF1, 4, 1); MM(aF4, bF2, 4, 2); MM(aF4, bF3, 4, 3); \
  MM(aF5, bF0, 5, 0); MM(aF5, bF1, 5, 1); MM(aF5, bF2, 5, 2); MM(aF5, bF3, 5, 3); \
  MM(aF6, bF0, 6, 0); MM(aF6, bF1, 6, 1); MM(aF6, bF2, 6, 2); MM(aF6, bF3, 6, 3); \
  MM(aF7, bF0, 7, 0); MM(aF7, bF1, 7, 1); MM(aF7, bF2, 7, 2); MM(aF7, bF3, 7, 3); \
  __builtin_amdgcn_s_setprio(0)

#define VMC4 asm volatile("s_waitcnt vmcnt(4)" ::: "memory")
#define VMC0 asm volatile("s_waitcnt vmcnt(0)" ::: "memory")
#define BAR  __builtin_amdgcn_s_barrier()

__global__ __launch_bounds__(512, 2) void gemm_kernel(
    const int8_t* __restrict__ xq,   // [8192][4096] i8
    const int8_t* __restrict__ cq,   // [4096][4096] i8 (circulant rows)
    const float* __restrict__ sx,    // [8192]
    const float* __restrict__ sc,    // [4096]
    const float* __restrict__ bias,  // [4096]
    float* __restrict__ out) {       // [8192][4096] fp32
  __shared__ __align__(16) char smem[4 * 32768];  // 128 KiB ring

  const int tid = threadIdx.x;
  const int w = tid >> 6, l = tid & 63;
  const int wr = w >> 2, wc = w & 3;       // 2 x 4 wave grid, wave owns 128x64
  // anti-phase group: one even + one odd wave per SIMD (SIMD = w % 4)
  const bool odd = (__builtin_amdgcn_readfirstlane(w) >> 2) & 1;

  // bijective XCD swizzle: 512 blocks = 8 XCDs x 64
  const int orig = blockIdx.x;
  const int wg = (orig & 7) * 64 + (orig >> 3);
  const int bm = (wg >> 4) * 256;
  const int bn = (wg & 15) * 256;

  // staging: phys row r = 16w + (l>>2) (+128 2nd copy); phys chunk = l&3;
  // stored logical chunk = (l&3) ^ ((l>>3)&3) -> pre-swizzled global col.
  const int sgr = w * 16 + (l >> 2);
  const int sgc = ((l & 3) ^ ((l >> 3) & 3)) << 4;
  const int8_t* sA = xq + (size_t)(bm + sgr) * IN_DIM + sgc;
  const int8_t* sB = cq + (size_t)(bn + sgr) * IN_DIM + sgc;

  // frag reads: row = 16-aligned base + (l&15), logical chunk (l>>4)
  //   -> phys chunk = (l>>4) ^ ((l>>1)&3)
  const int swz = ((l >> 4) ^ ((l >> 1) & 3)) << 4;
  const int aRd = (wr * 128 + (l & 15)) * 64 + swz;
  const int bRd = (wc * 64 + (l & 15)) * 64 + swz;

  i32x4 acc[8][4];
#pragma unroll
  for (int i = 0; i < 8; ++i)
#pragma unroll
    for (int j = 0; j < 4; ++j) acc[i][j] = (i32x4){0, 0, 0, 0};
  i32x4 aF0, aF1, aF2, aF3, aF4, aF5, aF6, aF7, bF0, bF1, bF2, bF3;

  // ---- prologue: stage ksteps 0,1,2; certify 0,1; odd preloads frags(0)
  STAGE(0, 0);
  STAGE(1, 64);
  STAGE(2, 128);
  VMC4;   // 12 issued, wait to 4 -> slots 0,1 landed
  BAR;
  if (odd) { READF(0); }

  // ---- main loop: bodies s = 0..59 (15 iters x 4)
  for (int it = 0; it < 15; ++it) {
    // body j: read slot j (even) / MFMA+read slot j+1 (odd); stage slot (j+3)&3
    STAGE(3, 192);
    if (odd) { MFMA32; READF(1); } else { READF(0); MFMA32; }
    VMC4; BAR;
    STAGE(0, 256);
    if (odd) { MFMA32; READF(2); } else { READF(1); MFMA32; }
    VMC4; BAR;
    STAGE(1, 320);
    if (odd) { MFMA32; READF(3); } else { READF(2); MFMA32; }
    VMC4; BAR;
    STAGE(2, 384);
    if (odd) { MFMA32; READF(0); } else { READF(3); MFMA32; }
    VMC4; BAR;
    sA += 256; sB += 256;
  }

  // ---- tail: bodies s = 60..63 (sA at kstep 60)
  STAGE(3, 192);                                      // stage kstep 63
  if (odd) { MFMA32; READF(1); } else { READF(0); MFMA32; }
  VMC4; BAR;                                          // certifies slot 2
  if (odd) { MFMA32; READF(2); } else { READF(1); MFMA32; }
  VMC0; BAR;                                          // certifies slot 3
  if (odd) { MFMA32; READF(3); } else { READF(2); MFMA32; }
  BAR;
  if (odd) { MFMA32; } else { READF(3); MFMA32; }

  // ---- epilogue: C/D layout col=lane&15, row=(lane>>4)*4+reg
#pragma unroll
  for (int mi = 0; mi < 8; ++mi) {
    const int row = bm + wr * 128 + mi * 16 + (l >> 4) * 4;
    const float4 sx4 = *(const float4*)(sx + row);
#pragma unroll
    for (int ni = 0; ni < 4; ++ni) {
      const int col = bn + wc * 64 + ni * 16 + (l & 15);
      const float scv = sc[col];
      const float bv = bias[col];
      float* po = out + (size_t)row * OUT_DIM + col;
      po[0 * (size_t)OUT_DIM] = (float)acc[mi][ni][0] * (sx4.x * scv) + bv;
      po[1 * (size_t)OUT_DIM] = (float)acc[mi][ni][1] * (sx4.y * scv) + bv;
      po[2 * (size_t)OUT_DIM] = (float)acc[mi][ni][2] * (sx4.z * scv) + bv;
      po[3 * (size_t)OUT_DIM] = (float)acc[mi][ni][3] * (sx4.w * scv) + bv;
    }
  }
}

// ---- host ---------------------------------------------------------------

extern "C" void kernel_launch(void* const* d_in, const int* in_sizes, int n_in,
                              void* d_out, int out_size, void* d_ws, size_t ws_size,
                              hipStream_t stream) {
  const float* x    = (const float*)d_in[0];
  const float* c    = (const float*)d_in[1];
  const float* bias = (const float*)d_in[2];
  float* out = (float*)d_out;

  const size_t xq_bytes = (size_t)B_DIM * IN_DIM;
  const size_t cq_bytes = (size_t)OUT_DIM * IN_DIM;
  const size_t need = xq_bytes + cq_bytes + (B_DIM + OUT_DIM) * sizeof(float);
  if (ws_size < need) return;

  int8_t* xq = (int8_t*)d_ws;
  int8_t* cq = xq + xq_bytes;
  float* sx = (float*)(cq + cq_bytes);
  float* sc = sx + B_DIM;

  quant_fused_kernel<<<B_DIM + OUT_DIM, 256, 0, stream>>>(x, c, xq, cq, sx, sc);

  const int grid = (B_DIM / 256) * (OUT_DIM / 256);  // 512
  gemm_kernel<<<grid, 512, 0, stream>>>(xq, cq, sx, sc, bias, out);
}

// Round 13
// 177.847 us; speedup vs baseline: 6.6123x; 6.6123x over previous
//
#include <hip/hip_runtime.h>
#include <hip/hip_bf16.h>
#include <stdint.h>

// CirculantLinear == dense GEMM: y[b,o] = sum_n x[b,n]*rows[o,n] + bias[o]
// where rows[o,n] = c[o, (4096-n) & 4095].
// M=8192, N=4096, K=4096. fp32 in/out.
// R9: i8 path (per-row symmetric quant + mfma_i32_16x16x64_i8), 256^2 tile,
//     BK=128, 8-phase: GEMM 140us, absmax 0.047. CHAMPION.
// R10/R12: overlap attempts -> scratch-spill disasters (reg cap / divergent
//     CFG around live accumulator). R11: smaller tile -> LDS-bound, worse.
// R13: R9 GEMM byte-for-byte + vectorized-reverse quant kernel (proven in
//     R10-R12): float4 c-path loads, saves ~16us of non-GEMM time.

#define B_DIM  8192
#define OUT_DIM 4096
#define IN_DIM  4096

typedef __attribute__((ext_vector_type(4))) int i32x4;

// ---- fused quantization kernel ------------------------------------------
// One block (256 thr) per row. x rows: blocks [0, B_DIM); c rows (with the
// circulant reverse-roll): blocks [B_DIM, B_DIM+OUT_DIM).

__global__ void quant_fused_kernel(const float* __restrict__ x,
                                   const float* __restrict__ c,
                                   int8_t* __restrict__ xq,
                                   int8_t* __restrict__ cq,
                                   float* __restrict__ sx,
                                   float* __restrict__ sc) {
  const int row = blockIdx.x;
  const int t = threadIdx.x;
  __shared__ float sm[4];
  float vals[16];

  if (row < B_DIM) {
    const float4* src = (const float4*)(x + (size_t)row * IN_DIM + t * 16);
#pragma unroll
    for (int j = 0; j < 4; ++j) {
      float4 v = src[j];
      vals[4 * j + 0] = v.x; vals[4 * j + 1] = v.y;
      vals[4 * j + 2] = v.z; vals[4 * j + 3] = v.w;
    }
  } else {
    const float* crow = c + (size_t)(row - B_DIM) * IN_DIM;
    const int n0 = t * 16;
    if (t == 0) {
#pragma unroll
      for (int j = 0; j < 16; ++j) vals[j] = crow[(IN_DIM - j) & (IN_DIM - 1)];
    } else {
      // s = 4096-n0-j for j=0..15: contiguous descending, no wrap for t>=1.
      const float4* src = (const float4*)(crow + (IN_DIM - n0 - 15));
      float f[16];
#pragma unroll
      for (int j = 0; j < 4; ++j) {
        float4 v = src[j];
        f[4 * j + 0] = v.x; f[4 * j + 1] = v.y;
        f[4 * j + 2] = v.z; f[4 * j + 3] = v.w;
      }
#pragma unroll
      for (int j = 0; j < 16; ++j) vals[j] = f[15 - j];
    }
  }

  float m = 0.f;
#pragma unroll
  for (int j = 0; j < 16; ++j) m = fmaxf(m, fabsf(vals[j]));
#pragma unroll
  for (int k = 32; k; k >>= 1) m = fmaxf(m, __shfl_xor(m, k));
  if ((t & 63) == 0) sm[t >> 6] = m;
  __syncthreads();
  m = fmaxf(fmaxf(sm[0], sm[1]), fmaxf(sm[2], sm[3]));

  const float inv = m > 0.f ? 127.0f / m : 0.f;
  const float scale = m * (1.0f / 127.0f);

  int4 packed;
  int* pw = (int*)&packed;
#pragma unroll
  for (int g = 0; g < 4; ++g) {
    int wbits = 0;
#pragma unroll
    for (int j = 0; j < 4; ++j) {
      float q = rintf(vals[g * 4 + j] * inv);
      q = fminf(fmaxf(q, -127.f), 127.f);
      wbits |= (((int)q) & 0xff) << (8 * j);
    }
    pw[g] = wbits;
  }

  if (row < B_DIM) {
    *(int4*)(xq + (size_t)row * IN_DIM + t * 16) = packed;
    if (t == 0) sx[row] = scale;
  } else {
    *(int4*)(cq + (size_t)(row - B_DIM) * IN_DIM + t * 16) = packed;
    if (t == 0) sc[row - B_DIM] = scale;
  }
}

// ---- GEMM (R9, byte-for-byte) -------------------------------------------

__device__ __forceinline__ void async_copy16(const void* g, void* l) {
  __builtin_amdgcn_global_load_lds(
      (const __attribute__((address_space(1))) void*)g,
      (__attribute__((address_space(3))) void*)l, 16, 0, 0);
}

#define SMEM_BUF 65536
// Per buffer: [A kh0 16K][A kh1 16K][B kh0 16K][B kh1 16K]; khalf = row-major
// [256 rows][64 B] (= 64 i8 k-elems), 4 x 16B chunks/row, chunk-XOR swizzle
// phys_chunk = logical ^ ((row>>1)&3) (measured 0 conflicts). Stage side
// applies the inverse via the per-lane GLOBAL address (LDS dest linear).
// One K-tile = 128 i8 k-elems (2 khalves); NT = 32.

template<int BUF, int KK, int MH, int SMAT, int SBUF, int SKK, int SOFF, int VM>
__device__ __forceinline__ void phase(char* smem, int aRd, int bRd, int w,
                                      const int8_t* sA, const int8_t* sB,
                                      i32x4* bF, i32x4* aF,
                                      i32x4 (*acc)[4]) {
  const char* base = smem + BUF * SMEM_BUF + KK * 16384;
  if (MH == 0) {
#pragma unroll
    for (int ni = 0; ni < 4; ++ni)
      bF[ni] = *(const i32x4*)(base + 32768 + bRd + ni * 1024);
#pragma unroll
    for (int mi = 0; mi < 4; ++mi)
      aF[mi] = *(const i32x4*)(base + aRd + mi * 1024);
  } else {
#pragma unroll
    for (int mi = 0; mi < 4; ++mi)
      aF[mi] = *(const i32x4*)(base + aRd + (4 + mi) * 1024);
  }
  if (SMAT >= 0) {
    const int8_t* src = (SMAT ? sB : sA) + SOFF;
    char* dst = smem + SBUF * SMEM_BUF + SMAT * 32768 + SKK * 16384 + w * 1024;
    async_copy16(src, dst);                        // rows 0..127 of khalf
    async_copy16(src + 128 * IN_DIM, dst + 8192);  // rows 128..255
  }
  __builtin_amdgcn_s_barrier();
  __builtin_amdgcn_s_setprio(1);
#pragma unroll
  for (int i = 0; i < 4; ++i)
#pragma unroll
    for (int ni = 0; ni < 4; ++ni)
      acc[MH * 4 + i][ni] = __builtin_amdgcn_mfma_i32_16x16x64_i8(
          aF[i], bF[ni], acc[MH * 4 + i][ni], 0, 0, 0);
  __builtin_amdgcn_s_setprio(0);
  if (VM == 4) asm volatile("s_waitcnt vmcnt(4)" ::: "memory");
  if (VM == 0) asm volatile("s_waitcnt vmcnt(0)" ::: "memory");
  __builtin_amdgcn_s_barrier();
}

__global__ __launch_bounds__(512, 2) void gemm_kernel(
    const int8_t* __restrict__ xq,   // [8192][4096] i8
    const int8_t* __restrict__ cq,   // [4096][4096] i8 (circulant rows)
    const float* __restrict__ sx,    // [8192] row scales of x
    const float* __restrict__ sc,    // [4096] row scales of c-rows
    const float* __restrict__ bias,  // [4096]
    float* __restrict__ out) {       // [8192][4096] fp32
  __shared__ __align__(16) char smem[2 * SMEM_BUF];  // 128 KiB

  const int tid = threadIdx.x;
  const int w = tid >> 6, l = tid & 63;
  const int wr = w >> 2, wc = w & 3;       // 2 x 4 wave grid, wave owns 128x64

  // bijective XCD swizzle: 512 blocks = 8 XCDs x 64
  const int orig = blockIdx.x;
  const int wg = (orig & 7) * 64 + (orig >> 3);
  const int bm = (wg >> 4) * 256;
  const int bn = (wg & 15) * 256;

  // staging: phys row r = 16w + (l>>2) (+128 2nd copy); phys chunk = l&3;
  // stored logical chunk = (l&3) ^ ((l>>3)&3) -> pre-swizzled global col.
  // chunk = 16 i8 elements.
  const int sgr = w * 16 + (l >> 2);
  const int sgc = ((l & 3) ^ ((l >> 3) & 3)) << 4;
  const int8_t* sA = xq + (size_t)(bm + sgr) * IN_DIM + sgc;
  const int8_t* sB = cq + (size_t)(bn + sgr) * IN_DIM + sgc;

  // frag reads: row = 16-aligned base + (l&15), logical chunk (l>>4)
  //   -> phys chunk = (l>>4) ^ ((l>>1)&3)   (byte offsets unchanged)
  const int swz = ((l >> 4) ^ ((l >> 1) & 3)) << 4;
  const int aRd = (wr * 128 + (l & 15)) * 64 + swz;
  const int bRd = (wc * 64 + (l & 15)) * 64 + swz;

  i32x4 acc[8][4];
#pragma unroll
  for (int i = 0; i < 8; ++i)
#pragma unroll
    for (int j = 0; j < 4; ++j) acc[i][j] = (i32x4){0, 0, 0, 0};
  i32x4 aF[4], bF[4];

  // ---- prologue: stage K-tile 0 into buf0 (A-kh0, B-kh0, A-kh1, B-kh1)
  {
    async_copy16(sA,                smem + 0 + w * 1024);
    async_copy16(sA + 128 * IN_DIM, smem + 0 + 8192 + w * 1024);
    async_copy16(sB,                smem + 32768 + w * 1024);
    async_copy16(sB + 128 * IN_DIM, smem + 32768 + 8192 + w * 1024);
    async_copy16(sA + 64,                smem + 16384 + w * 1024);
    async_copy16(sA + 64 + 128 * IN_DIM, smem + 16384 + 8192 + w * 1024);
    async_copy16(sB + 64,                smem + 32768 + 16384 + w * 1024);
    async_copy16(sB + 64 + 128 * IN_DIM, smem + 32768 + 16384 + 8192 + w * 1024);
  }
  sA += 128; sB += 128;   // -> K-tile 1 (first staged in loop)
  asm volatile("s_waitcnt vmcnt(4)" ::: "memory");  // kh0 A+B landed
  __builtin_amdgcn_s_barrier();

  // ---- main loop: 2 K-tiles per iteration, kt = 0..29 (15 iters)
  for (int it = 0; it < 15; ++it) {
    // kt even: compute buf0, stage kt+1 -> buf1
    phase<0,0,0,  0,1,0,   0, -1>(smem, aRd, bRd, w, sA, sB, bF, aF, acc);
    phase<0,0,1,  1,1,0,   0,  4>(smem, aRd, bRd, w, sA, sB, bF, aF, acc);
    phase<0,1,0,  0,1,1,  64, -1>(smem, aRd, bRd, w, sA, sB, bF, aF, acc);
    phase<0,1,1,  1,1,1,  64,  4>(smem, aRd, bRd, w, sA, sB, bF, aF, acc);
    // kt odd: compute buf1, stage kt+2 -> buf0
    phase<1,0,0,  0,0,0, 128, -1>(smem, aRd, bRd, w, sA, sB, bF, aF, acc);
    phase<1,0,1,  1,0,0, 128,  4>(smem, aRd, bRd, w, sA, sB, bF, aF, acc);
    phase<1,1,0,  0,0,1, 192, -1>(smem, aRd, bRd, w, sA, sB, bF, aF, acc);
    phase<1,1,1,  1,0,1, 192,  4>(smem, aRd, bRd, w, sA, sB, bF, aF, acc);
    sA += 256; sB += 256;
  }
  // kt=30: compute buf0, stage kt31 -> buf1
  phase<0,0,0,  0,1,0,   0, -1>(smem, aRd, bRd, w, sA, sB, bF, aF, acc);
  phase<0,0,1,  1,1,0,   0,  4>(smem, aRd, bRd, w, sA, sB, bF, aF, acc);
  phase<0,1,0,  0,1,1,  64, -1>(smem, aRd, bRd, w, sA, sB, bF, aF, acc);
  phase<0,1,1,  1,1,1,  64,  4>(smem, aRd, bRd, w, sA, sB, bF, aF, acc);
  // kt=31: compute buf1, no staging; drain kh1 before its phase-3/4 reads
  phase<1,0,0, -1,0,0,   0, -1>(smem, aRd, bRd, w, sA, sB, bF, aF, acc);
  phase<1,0,1, -1,0,0,   0,  0>(smem, aRd, bRd, w, sA, sB, bF, aF, acc);
  phase<1,1,0, -1,0,0,   0, -1>(smem, aRd, bRd, w, sA, sB, bF, aF, acc);
  phase<1,1,1, -1,0,0,   0, -1>(smem, aRd, bRd, w, sA, sB, bF, aF, acc);

  // ---- epilogue: C/D layout col=lane&15, row=(lane>>4)*4+reg
  // (dtype-independent on gfx950; i8 cell verified m121)
#pragma unroll
  for (int mi = 0; mi < 8; ++mi) {
    const int row = bm + wr * 128 + mi * 16 + (l >> 4) * 4;
    const float4 sx4 = *(const float4*)(sx + row);   // rows row..row+3
#pragma unroll
    for (int ni = 0; ni < 4; ++ni) {
      const int col = bn + wc * 64 + ni * 16 + (l & 15);
      const float scv = sc[col];
      const float bv = bias[col];
      float* po = out + (size_t)row * OUT_DIM + col;
      po[0 * (size_t)OUT_DIM] = (float)acc[mi][ni][0] * (sx4.x * scv) + bv;
      po[1 * (size_t)OUT_DIM] = (float)acc[mi][ni][1] * (sx4.y * scv) + bv;
      po[2 * (size_t)OUT_DIM] = (float)acc[mi][ni][2] * (sx4.z * scv) + bv;
      po[3 * (size_t)OUT_DIM] = (float)acc[mi][ni][3] * (sx4.w * scv) + bv;
    }
  }
}

// ---- host ---------------------------------------------------------------

extern "C" void kernel_launch(void* const* d_in, const int* in_sizes, int n_in,
                              void* d_out, int out_size, void* d_ws, size_t ws_size,
                              hipStream_t stream) {
  const float* x    = (const float*)d_in[0];
  const float* c    = (const float*)d_in[1];
  const float* bias = (const float*)d_in[2];
  float* out = (float*)d_out;

  const size_t xq_bytes = (size_t)B_DIM * IN_DIM;
  const size_t cq_bytes = (size_t)OUT_DIM * IN_DIM;
  const size_t need = xq_bytes + cq_bytes + (B_DIM + OUT_DIM) * sizeof(float);
  if (ws_size < need) return;

  int8_t* xq = (int8_t*)d_ws;
  int8_t* cq = xq + xq_bytes;
  float* sx = (float*)(cq + cq_bytes);
  float* sc = sx + B_DIM;

  quant_fused_kernel<<<B_DIM + OUT_DIM, 256, 0, stream>>>(x, c, xq, cq, sx, sc);

  const int grid = (B_DIM / 256) * (OUT_DIM / 256);  // 512
  gemm_kernel<<<grid, 512, 0, stream>>>(xq, cq, sx, sc, bias, out);
}